// Round 8
// baseline (945.401 us; speedup 1.0000x reference)
//
#include <hip/hip_runtime.h>
#include <hip/hip_bf16.h>

using bf16 = __hip_bfloat16;
typedef __bf16 bf16x8 __attribute__((ext_vector_type(8)));
typedef unsigned short u16x8 __attribute__((ext_vector_type(8)));
typedef float f32x4 __attribute__((ext_vector_type(4)));
typedef float f32x2 __attribute__((ext_vector_type(2)));
typedef int   i32x4 __attribute__((ext_vector_type(4)));
typedef int   i32x8 __attribute__((ext_vector_type(8)));

#define LOG_SQRT_2PI 0.91893853320467274f

static constexpr int BSZ  = 16384;
static constexpr int OBSN = 376;
static constexpr int KP   = 384;   // padded OBS
static constexpr int HD   = 512;
static constexpr int NACT = 17;

#define BM 128
#define BN 128
#define BK 32

__device__ __forceinline__ float bf2f(unsigned short u) {
  return __uint_as_float((unsigned)u << 16);
}
__device__ __forceinline__ unsigned char f2fp8(float v) {
  return (unsigned char)(__builtin_amdgcn_cvt_pk_fp8_f32(v, v, 0, false) & 0xFF);
}

// XCD-aware tile remap: blocks sharing an A-tile (same y,z; all x) get consecutive
// slots on the SAME XCD (id%8 round-robin). Requires gy*gz % 8 == 0.
__device__ __forceinline__ void xcd_map(int id, int gx, int gy, int& bx, int& by, int& bz) {
  int p = id & 7, l = id >> 3;
  bx = l % gx;
  int g = (l / gx) * 8 + p;
  by = g % gy;
  bz = g / gy;
}

// ---------------- prep kernels ----------------

__global__ void k_cvt_pad(const float* __restrict__ src, bf16* __restrict__ dst,
                          long total, int K, int Kpad) {
  long i = (long)blockIdx.x * 256 + threadIdx.x;
  if (i >= total) return;
  long r = i / Kpad;
  int  c = (int)(i - r * Kpad);
  dst[i] = __float2bfloat16(c < K ? src[r * K + c] : 0.f);
}

// dst[n][k] = src[k][n] (f32 -> bf16), batched via blockIdx.z
__global__ void k_transpose(const float* __restrict__ src, bf16* __restrict__ dst,
                            int K, int N, int Kpad, long sstride, long dstride) {
  __shared__ float t[32][33];
  src += (long)blockIdx.z * sstride;
  dst += (long)blockIdx.z * dstride;
  int k0 = blockIdx.y * 32, n0 = blockIdx.x * 32;
#pragma unroll
  for (int ii = 0; ii < 4; ++ii) {
    int i = ii * 8 + threadIdx.y;
    int k = k0 + i, n = n0 + threadIdx.x;
    t[i][threadIdx.x] = (k < K && n < N) ? src[(long)k * N + n] : 0.f;
  }
  __syncthreads();
#pragma unroll
  for (int ii = 0; ii < 4; ++ii) {
    int i = ii * 8 + threadIdx.y;
    int n = n0 + i, k = k0 + threadIdx.x;
    if (n < N && k < Kpad) dst[(long)n * Kpad + k] = __float2bfloat16(t[threadIdx.x][i]);
  }
}

// base-net weights: dst[z][n][k] = fp8(16 * src_z[k][n]); z<24 -> a_W, else c_W
__global__ void k_packw8(const float* __restrict__ aW, const float* __restrict__ cW,
                         unsigned char* __restrict__ dst) {
  __shared__ float t[32][33];
  const int z = blockIdx.z;
  const float* src = (z < 24) ? aW + (long)z * 262144 : cW + (long)(z - 24) * 262144;
  unsigned char* d = dst + (long)z * 262144;
  int k0 = blockIdx.y * 32, n0 = blockIdx.x * 32;
#pragma unroll
  for (int ii = 0; ii < 4; ++ii) {
    int i = ii * 8 + threadIdx.y;
    t[i][threadIdx.x] = src[(long)(k0 + i) * 512 + n0 + threadIdx.x];
  }
  __syncthreads();
#pragma unroll
  for (int ii = 0; ii < 4; ++ii) {
    int i = ii * 8 + threadIdx.y;
    d[(long)(n0 + i) * 512 + k0 + threadIdx.x] = f2fp8(16.f * t[threadIdx.x][i]);
  }
}

// final-head weights -> fp8, x64 scaled, transposed [32 pad][4096]
__global__ void k_packwf8(const float* __restrict__ aWf, const float* __restrict__ cWf,
                          unsigned char* __restrict__ dsta, unsigned char* __restrict__ dstc) {
  int i = blockIdx.x * 256 + threadIdx.x;   // 131072 total
  int n = i >> 12, k = i & 4095;
  dsta[i] = (n < NACT) ? f2fp8(64.f * aWf[(long)k * NACT + n]) : (unsigned char)0;
  dstc[i] = (n < 1)    ? f2fp8(64.f * cWf[k])                  : (unsigned char)0;
}

__global__ void k_pack_rb(const float* __restrict__ a_rb, const float* __restrict__ c_rb,
                          float* __restrict__ rb) {
  int i = threadIdx.x;  // 384 threads
  rb[i] = (i < 192) ? a_rb[i] : c_rb[i - 192];
}

__global__ void k_sum_bf(const float* __restrict__ a_bf, const float* __restrict__ c_bf,
                         float* __restrict__ sa, float* __restrict__ sc) {
  int a = threadIdx.x;
  if (a < NACT) { float s = 0.f; for (int m = 0; m < 8; ++m) s += a_bf[m * NACT + a]; sa[a] = s; }
  if (a == 0)   { float s = 0.f; for (int m = 0; m < 8; ++m) s += c_bf[m];            sc[0] = s; }
}

// ---------------- bf16 GEMM (encoder / routing): C = A[rows,K] * Bt[N,K]^T ----------------
// OP: 1 = bias+tanh -> bf16
//     4 = bias, softmax over col-groups of 8 -> f32 (routing)
//     5 = bias+tanh -> fp8 (fs8) AND relu(tanh*temb[tidx]) -> bf16 (rel, out2)
template <int OP>
__global__ __launch_bounds__(256)
void k_gemm(const bf16* __restrict__ A, const bf16* __restrict__ Bt,
            void* __restrict__ Cv, const float* __restrict__ bias,
            int N, int K, int lda, int ldc, int gx, int gy,
            const int* __restrict__ tidx, const float* __restrict__ temb,
            bf16* __restrict__ out2) {
  __shared__ alignas(16) bf16 sA[BM * BK];
  __shared__ alignas(16) bf16 sB[BN * BK];
  int bx, by, bz;
  xcd_map(blockIdx.x, gx, gy, bx, by, bz);
  const int tid  = threadIdx.x;
  const int wave = tid >> 6, lane = tid & 63;
  const int wr = (wave >> 1) * 64, wc = (wave & 1) * 64;
  const int row0 = by * BM, col0 = bx * BN;
  const int lcol = lane & 15, quad = lane >> 4;
  const int sw = (lcol >> 1) & 3;       // lane-constant swizzle
  const int chq = (quad ^ sw) * 8;      // swizzled element offset of this lane's chunk

  f32x4 acc[4][4] = {};

  for (int kt = 0; kt < K; kt += BK) {
#pragma unroll
    for (int i = 0; i < 2; ++i) {
      int u = i * 256 + tid;
      int r = u >> 2, gc = (u & 3) ^ ((u >> 3) & 3);
      const bf16* ga = A  + (long)(row0 + r) * lda + (kt + gc * 8);
      const bf16* gb = Bt + (long)(col0 + r) * K   + (kt + gc * 8);
      __builtin_amdgcn_global_load_lds((const __attribute__((address_space(1))) void*)ga,
                                       (__attribute__((address_space(3))) void*)&sA[u * 8], 16, 0, 0);
      __builtin_amdgcn_global_load_lds((const __attribute__((address_space(1))) void*)gb,
                                       (__attribute__((address_space(3))) void*)&sB[u * 8], 16, 0, 0);
    }
    __syncthreads();
    bf16x8 af[4], bv[4];
#pragma unroll
    for (int t = 0; t < 4; ++t) {
      af[t] = *(const bf16x8*)&sA[(wr + t * 16 + lcol) * BK + chq];
      bv[t] = *(const bf16x8*)&sB[(wc + t * 16 + lcol) * BK + chq];
    }
#pragma unroll
    for (int mi = 0; mi < 4; ++mi)
#pragma unroll
      for (int ni = 0; ni < 4; ++ni)
        acc[mi][ni] = __builtin_amdgcn_mfma_f32_16x16x32_bf16(af[mi], bv[ni], acc[mi][ni], 0, 0, 0);
    __syncthreads();
  }

#pragma unroll
  for (int ni = 0; ni < 4; ++ni) {
    int colg = col0 + wc + ni * 16 + lcol;
    if (colg >= N) continue;
    float bvv = bias[colg];
#pragma unroll
    for (int mi = 0; mi < 4; ++mi) {
#pragma unroll
      for (int r = 0; r < 4; ++r) {
        int rowg = row0 + wr + mi * 16 + quad * 4 + r;
        float v = acc[mi][ni][r] + bvv;
        long idx = (long)rowg * ldc + colg;
        if (OP == 1) {
          ((bf16*)Cv)[idx] = __float2bfloat16(tanhf(v));
        } else if (OP == 4) {
          float mx = v;
          mx = fmaxf(mx, __shfl_xor(mx, 1));
          mx = fmaxf(mx, __shfl_xor(mx, 2));
          mx = fmaxf(mx, __shfl_xor(mx, 4));
          float e = __expf(v - mx);
          float s = e;
          s += __shfl_xor(s, 1);
          s += __shfl_xor(s, 2);
          s += __shfl_xor(s, 4);
          ((float*)Cv)[idx] = e / s;
        } else if (OP == 5) {
          float t = tanhf(v);
          ((unsigned char*)Cv)[idx] = f2fp8(t);
          int tk = tidx[rowg];
          float te = temb[(long)tk * HD + colg];
          out2[idx] = __float2bfloat16(fmaxf(t * te, 0.f));
        }
      }
    }
  }
}

// ---------------- MX fp8 GEMM: C8 = relu(A8[rows,K] * (16*W)^T * (1/16) + bias) ----------------
// K=128 per MFMA via mfma_scale_f32_16x16x128_f8f6f4 (scales = 1.0, fmt 0 = e4m3).
// LDS rows are 128 B; 16-B chunk g of row r stored at slot g ^ (r&7).
// Operands SWAPPED (bv first) so each lane's 4 acc regs = 4 consecutive C cols -> dword stores.
__global__ __launch_bounds__(256)
void k_gemm8(const unsigned char* __restrict__ A, const unsigned char* __restrict__ Bt,
             unsigned char* __restrict__ C, const float* __restrict__ bias,
             int N, int K, int lda, int ldc, int gx, int gy,
             int a_zoff, int b_zoff, int c_zoff, int bias_zoff) {
  __shared__ alignas(16) unsigned char sA[128 * 128];
  __shared__ alignas(16) unsigned char sB[128 * 128];
  int bx, by, z;
  xcd_map(blockIdx.x, gx, gy, bx, by, z);
  A  += (long)z * a_zoff;
  Bt += (long)z * b_zoff;
  const int tid  = threadIdx.x;
  const int wave = tid >> 6, lane = tid & 63;
  const int wr = (wave >> 1) * 64, wc = (wave & 1) * 64;
  const int row0 = by * 128, col0 = bx * 128;
  const int lcol = lane & 15, quad = lane >> 4;
  const int sw7 = lcol & 7;
  const int c0 = ((2 * quad)     ^ sw7) * 16;   // stored offset of global chunk 2q
  const int c1 = ((2 * quad + 1) ^ sw7) * 16;   // stored offset of global chunk 2q+1

  f32x4 acc[4][4] = {};

  for (int kt = 0; kt < K; kt += 128) {
#pragma unroll
    for (int i = 0; i < 4; ++i) {
      int u = i * 256 + tid;
      int r = u >> 3, gc = (u & 7) ^ (r & 7);
      const unsigned char* ga = A + (long)(row0 + r) * lda + kt + gc * 16;
      __builtin_amdgcn_global_load_lds((const __attribute__((address_space(1))) void*)ga,
                                       (__attribute__((address_space(3))) void*)&sA[u * 16], 16, 0, 0);
    }
#pragma unroll
    for (int i = 0; i < 4; ++i) {
      int u = i * 256 + tid;
      int r = u >> 3, gc = (u & 7) ^ (r & 7);
      const unsigned char* gb = Bt + (long)(col0 + r) * K + kt + gc * 16;
      __builtin_amdgcn_global_load_lds((const __attribute__((address_space(1))) void*)gb,
                                       (__attribute__((address_space(3))) void*)&sB[u * 16], 16, 0, 0);
    }
    __syncthreads();
    i32x8 af[4], bv[4];
#pragma unroll
    for (int t = 0; t < 4; ++t) {
      int ra = (wr + t * 16 + lcol) * 128;
      int rb = (wc + t * 16 + lcol) * 128;
      i32x4 alo = *(const i32x4*)&sA[ra + c0];
      i32x4 ahi = *(const i32x4*)&sA[ra + c1];
      i32x4 blo = *(const i32x4*)&sB[rb + c0];
      i32x4 bhi = *(const i32x4*)&sB[rb + c1];
      af[t] = (i32x8){alo[0], alo[1], alo[2], alo[3], ahi[0], ahi[1], ahi[2], ahi[3]};
      bv[t] = (i32x8){blo[0], blo[1], blo[2], blo[3], bhi[0], bhi[1], bhi[2], bhi[3]};
    }
#pragma unroll
    for (int mi = 0; mi < 4; ++mi)
#pragma unroll
      for (int ni = 0; ni < 4; ++ni)
        acc[mi][ni] = __builtin_amdgcn_mfma_scale_f32_16x16x128_f8f6f4(
            bv[ni], af[mi], acc[mi][ni], 0, 0, 0, 0x7F, 0, 0x7F);
    __syncthreads();
  }

  // acc[mi][ni][r] = C[row0+wr+mi*16+lcol][col0+wc+ni*16+quad*4+r]
#pragma unroll
  for (int ni = 0; ni < 4; ++ni) {
    int colb = col0 + wc + ni * 16 + quad * 4;
    if (colb >= N) continue;
    float4 bw = *(const float4*)&bias[(long)z * bias_zoff + colb];
#pragma unroll
    for (int mi = 0; mi < 4; ++mi) {
      int rowg = row0 + wr + mi * 16 + lcol;
      float v0 = fmaxf(acc[mi][ni][0] * 0.0625f + bw.x, 0.f);
      float v1 = fmaxf(acc[mi][ni][1] * 0.0625f + bw.y, 0.f);
      float v2 = fmaxf(acc[mi][ni][2] * 0.0625f + bw.z, 0.f);
      float v3 = fmaxf(acc[mi][ni][3] * 0.0625f + bw.w, 0.f);
      unsigned d = __builtin_amdgcn_cvt_pk_fp8_f32(v0, v1, 0, false);
      d = __builtin_amdgcn_cvt_pk_fp8_f32(v2, v3, d, true);
      *(unsigned*)&C[(long)rowg * ldc + (long)z * c_zoff + colb] = d;
    }
  }
}

// ---------------- fp8 combine: g[b][i][h] = sum_j probs[b][i][j] * outs[b][j][h] ----------------
__global__ __launch_bounds__(256)
void k_combine8(const unsigned char* __restrict__ outs, const float* __restrict__ probs,
                unsigned char* __restrict__ g, int poff) {
  __shared__ float P[4][64];
  const int w = threadIdx.x >> 6, l = threadIdx.x & 63;
  const long b = (long)blockIdx.x * 4 + w;
  P[w][l] = probs[b * 384 + poff + l];
  __syncthreads();
  const unsigned char* ob = outs + b * 4096 + l * 8;
  float o[8][8];
#pragma unroll
  for (int j = 0; j < 8; ++j) {
    uint2 v = *(const uint2*)(ob + j * 512);
    f32x2 p01 = __builtin_amdgcn_cvt_pk_f32_fp8(v.x, false);
    f32x2 p23 = __builtin_amdgcn_cvt_pk_f32_fp8(v.x, true);
    f32x2 p45 = __builtin_amdgcn_cvt_pk_f32_fp8(v.y, false);
    f32x2 p67 = __builtin_amdgcn_cvt_pk_f32_fp8(v.y, true);
    o[j][0] = p01.x; o[j][1] = p01.y; o[j][2] = p23.x; o[j][3] = p23.y;
    o[j][4] = p45.x; o[j][5] = p45.y; o[j][6] = p67.x; o[j][7] = p67.y;
  }
  unsigned char* gb = g + b * 4096 + l * 8;
#pragma unroll
  for (int i = 0; i < 8; ++i) {
    float a[8] = {};
#pragma unroll
    for (int j = 0; j < 8; ++j) {
      float pw = P[w][i * 8 + j];
#pragma unroll
      for (int c = 0; c < 8; ++c) a[c] += pw * o[j][c];
    }
    unsigned int lo = __builtin_amdgcn_cvt_pk_fp8_f32(a[0], a[1], 0, false);
    lo = __builtin_amdgcn_cvt_pk_fp8_f32(a[2], a[3], lo, true);
    unsigned int hi = __builtin_amdgcn_cvt_pk_fp8_f32(a[4], a[5], 0, false);
    hi = __builtin_amdgcn_cvt_pk_fp8_f32(a[6], a[7], hi, true);
    *(uint2*)(gb + i * 512) = make_uint2(lo, hi);
  }
}

// ---------------- MFMA head: out[:, ooff..ooff+NOUT) = g8[rows,4096] * (64*Wf)^T / 64 + bsum ----
template <int NOUT>
__global__ __launch_bounds__(256)
void k_head8(const unsigned char* __restrict__ A, const unsigned char* __restrict__ Bt,
             const float* __restrict__ bsum, float* __restrict__ out, int ooff) {
  __shared__ alignas(16) unsigned char sA[64 * 64];
  __shared__ alignas(16) unsigned char sB[32 * 64];
  const int tid = threadIdx.x;
  const int wave = tid >> 6, lane = tid & 63;
  const int row0 = blockIdx.x * 64;
  const int lcol = lane & 15, quad = lane >> 4;
  const int sw = (lcol >> 1) & 3;
  const int co0 = (((quad >> 1)    ) ^ sw) * 16 + (quad & 1) * 8;
  const int co1 = (((quad >> 1) + 2) ^ sw) * 16 + (quad & 1) * 8;
  f32x4 acc[2] = {};

  for (int kt = 0; kt < 4096; kt += 64) {
    {
      int r = tid >> 2, gc = (tid & 3) ^ ((tid >> 3) & 3);
      const unsigned char* ga = A + (long)(row0 + r) * 4096 + kt + gc * 16;
      __builtin_amdgcn_global_load_lds((const __attribute__((address_space(1))) void*)ga,
                                       (__attribute__((address_space(3))) void*)&sA[tid * 16], 16, 0, 0);
    }
    if (tid < 128) {
      int r = tid >> 2, gc = (tid & 3) ^ ((tid >> 3) & 3);
      const unsigned char* gb = Bt + (long)r * 4096 + kt + gc * 16;
      __builtin_amdgcn_global_load_lds((const __attribute__((address_space(1))) void*)gb,
                                       (__attribute__((address_space(3))) void*)&sB[tid * 16], 16, 0, 0);
    }
    __syncthreads();
    long af[2], bv[2][2];
    int ra = (wave * 16 + lcol) * 64;
    af[0] = *(const long*)&sA[ra + co0];
    af[1] = *(const long*)&sA[ra + co1];
#pragma unroll
    for (int ni = 0; ni < 2; ++ni) {
      int rb = (ni * 16 + lcol) * 64;
      bv[0][ni] = *(const long*)&sB[rb + co0];
      bv[1][ni] = *(const long*)&sB[rb + co1];
    }
#pragma unroll
    for (int kk = 0; kk < 2; ++kk)
#pragma unroll
      for (int ni = 0; ni < 2; ++ni)
        acc[ni] = __builtin_amdgcn_mfma_f32_16x16x32_fp8_fp8(af[kk], bv[kk][ni], acc[ni], 0, 0, 0);
    __syncthreads();
  }

#pragma unroll
  for (int ni = 0; ni < 2; ++ni) {
    int col = ni * 16 + lcol;
    if (col >= NOUT) continue;
#pragma unroll
    for (int r = 0; r < 4; ++r) {
      int row = row0 + wave * 16 + quad * 4 + r;
      out[(long)row * 20 + ooff + col] = acc[ni][r] * 0.015625f + bsum[col];
    }
  }
}

__global__ void k_logstd(const float* __restrict__ ls, float* __restrict__ out) {
  float lp = 0.f, ent = 0.f;
#pragma unroll
  for (int a = 0; a < NACT; ++a) {
    float v = ls[a];
    lp  += -v - LOG_SQRT_2PI;
    ent += 0.5f + LOG_SQRT_2PI + v;
  }
  long b = (long)blockIdx.x * 256 + threadIdx.x;
  if (b < BSZ) { out[b * 20 + 17] = lp; out[b * 20 + 18] = ent; }
}

// ---------------- host ----------------

extern "C" void kernel_launch(void* const* d_in, const int* in_sizes, int n_in,
                              void* d_out, int out_size, void* d_ws, size_t ws_size,
                              hipStream_t stream) {
  const float* x        = (const float*)d_in[0];
  const int*   task_idx = (const int*)d_in[1];
  const float* enc_W1   = (const float*)d_in[2];
  const float* enc_b1   = (const float*)d_in[3];
  const float* enc_W2   = (const float*)d_in[4];
  const float* enc_b2   = (const float*)d_in[5];
  const float* task_emb = (const float*)d_in[6];
  const float* a_rW     = (const float*)d_in[7];
  const float* a_rb     = (const float*)d_in[8];
  const float* c_rW     = (const float*)d_in[9];
  const float* c_rb     = (const float*)d_in[10];
  const float* a_W      = (const float*)d_in[11];
  const float* a_b      = (const float*)d_in[12];
  const float* a_Wf     = (const float*)d_in[13];
  const float* a_bf     = (const float*)d_in[14];
  const float* c_W      = (const float*)d_in[15];
  const float* c_b      = (const float*)d_in[16];
  const float* c_Wf     = (const float*)d_in[17];
  const float* c_bf     = (const float*)d_in[18];
  const float* logstd   = (const float*)d_in[19];
  float* out = (float*)d_out;

  char* ws = (char*)d_ws;
  size_t off = 0;
  auto carve = [&](size_t bytes) {
    char* p = ws + off;
    off += (bytes + 255) & ~(size_t)255;
    return p;
  };
  // ---- fixed region ----
  unsigned char* W8 = (unsigned char*)carve((size_t)48 * 262144);   // fp8 layer weights, x16 scaled
  bf16* W1T    = (bf16*)carve((size_t)512 * KP * 2);
  bf16* W2T    = (bf16*)carve((size_t)512 * 512 * 2);
  bf16* rWT    = (bf16*)carve((size_t)384 * 512 * 2);
  float* rball = (float*)carve(384 * 4);
  unsigned char* WfaT8 = (unsigned char*)carve((size_t)32 * 4096);  // fp8 head weights, x64 scaled, padded
  unsigned char* WfcT8 = (unsigned char*)carve((size_t)32 * 4096);
  float* bfa   = (float*)carve(128 * 4);
  float* bfc   = (float*)carve(128 * 4);
  unsigned char* fs8 = (unsigned char*)carve((size_t)BSZ * HD);
  float* lgt   = (float*)carve((size_t)BSZ * 384 * 4);

  // ---- chunked fp8 ping-pong region; cap Bc at 8192 so hot set stays L3-resident ----
  size_t remain = (ws_size > off) ? (ws_size - off) : 0;
  int Bc = 4096;
  for (int cand = 8192; cand > 4096; cand >>= 1)
    if ((size_t)2 * cand * 4096 <= remain) { Bc = cand; break; }
  size_t half = (size_t)Bc * 4096;
  unsigned char* bufA8 = (unsigned char*)carve(half);
  unsigned char* bufB8 = (unsigned char*)carve(half);
  bf16* xpad = (bf16*)bufA8;   // 12.6 MB <= half (half >= 16.8 MB for Bc >= 4096)
  bf16* h1   = (bf16*)bufB8;
  bf16* rel  = (bf16*)bufA8;

  dim3 tb(32, 8);

  // ---- prep ----
  k_cvt_pad<<<(int)(((long)BSZ * KP + 255) / 256), 256, 0, stream>>>(x, xpad, (long)BSZ * KP, OBSN, KP);
  k_transpose<<<dim3(16, 12, 1),  tb, 0, stream>>>(enc_W1, W1T, OBSN, 512, KP, 0, 0);
  k_transpose<<<dim3(16, 16, 1),  tb, 0, stream>>>(enc_W2, W2T, 512, 512, 512, 0, 0);
  k_transpose<<<dim3(2, 16, 3),   tb, 0, stream>>>(a_rW, rWT,             512, 64, 512, 512 * 64, 64 * 512);
  k_transpose<<<dim3(2, 16, 3),   tb, 0, stream>>>(c_rW, rWT + 192 * 512, 512, 64, 512, 512 * 64, 64 * 512);
  k_packw8<<<dim3(16, 16, 48), tb, 0, stream>>>(a_W, c_W, W8);
  k_packwf8<<<512, 256, 0, stream>>>(a_Wf, c_Wf, WfaT8, WfcT8);
  k_pack_rb<<<1, 384, 0, stream>>>(a_rb, c_rb, rball);
  k_sum_bf<<<1, 32, 0, stream>>>(a_bf, c_bf, bfa, bfc);

  // ---- encoder (bf16), XCD-remapped 1-D grids ----
  k_gemm<1><<<4 * (BSZ / BM), 256, 0, stream>>>(xpad, W1T, h1, enc_b1, 512, KP, KP, 512,
                                                4, BSZ / BM, nullptr, nullptr, nullptr);
  k_gemm<5><<<4 * (BSZ / BM), 256, 0, stream>>>(h1, W2T, fs8, enc_b2, 512, 512, 512, 512,
                                                4, BSZ / BM, task_idx, task_emb, rel);
  k_gemm<4><<<3 * (BSZ / BM), 256, 0, stream>>>(rel, rWT, lgt, rball, 384, 512, 512, 384,
                                                3, BSZ / BM, nullptr, nullptr, nullptr);

  // ---- base nets (fp8 MX), chunked ----
  const size_t wz8 = (size_t)8 * 262144;
  const unsigned char* W8a = W8;
  const unsigned char* W8c = W8 + (size_t)24 * 262144;
  for (int c0 = 0; c0 < BSZ; c0 += Bc) {
    const unsigned char* fs_c = fs8 + (long)c0 * 512;
    const float* pr_c  = lgt + (long)c0 * 384;
    float*       out_c = out + (long)c0 * 20;
    const int gy = Bc / 128;

    // critic
    k_gemm8<<<32 * gy, 256, 0, stream>>>(fs_c, W8c, bufA8, c_b, 4096, 512, 512, 4096,
                                         32, gy, 0, 0, 0, 0);
    k_combine8<<<Bc / 4, 256, 0, stream>>>(bufA8, pr_c, bufB8, 192 + 0);
    k_gemm8<<<4 * gy * 8, 256, 0, stream>>>(bufB8, W8c + 1 * wz8, bufA8, c_b + 4096,
                                            512, 512, 4096, 4096, 4, gy, 512, 262144, 512, 512);
    k_combine8<<<Bc / 4, 256, 0, stream>>>(bufA8, pr_c, bufB8, 192 + 64);
    k_gemm8<<<4 * gy * 8, 256, 0, stream>>>(bufB8, W8c + 2 * wz8, bufA8, c_b + 8192,
                                            512, 512, 4096, 4096, 4, gy, 512, 262144, 512, 512);
    k_combine8<<<Bc / 4, 256, 0, stream>>>(bufA8, pr_c, bufB8, 192 + 128);
    k_head8<1><<<Bc / 64, 256, 0, stream>>>(bufB8, WfcT8, bfc, out_c, 19);

    // actor
    k_gemm8<<<32 * gy, 256, 0, stream>>>(fs_c, W8a, bufA8, a_b, 4096, 512, 512, 4096,
                                         32, gy, 0, 0, 0, 0);
    k_combine8<<<Bc / 4, 256, 0, stream>>>(bufA8, pr_c, bufB8, 0);
    k_gemm8<<<4 * gy * 8, 256, 0, stream>>>(bufB8, W8a + 1 * wz8, bufA8, a_b + 4096,
                                            512, 512, 4096, 4096, 4, gy, 512, 262144, 512, 512);
    k_combine8<<<Bc / 4, 256, 0, stream>>>(bufA8, pr_c, bufB8, 64);
    k_gemm8<<<4 * gy * 8, 256, 0, stream>>>(bufB8, W8a + 2 * wz8, bufA8, a_b + 8192,
                                            512, 512, 4096, 4096, 4, gy, 512, 262144, 512, 512);
    k_combine8<<<Bc / 4, 256, 0, stream>>>(bufA8, pr_c, bufB8, 128);
    k_head8<NACT><<<Bc / 64, 256, 0, stream>>>(bufB8, WfaT8, bfa, out_c, 0);
  }

  // ---- constants ----
  k_logstd<<<BSZ / 256, 256, 0, stream>>>(logstd, out);
}

// Round 9
// 837.499 us; speedup vs baseline: 1.1288x; 1.1288x over previous
//
#include <hip/hip_runtime.h>
#include <hip/hip_bf16.h>

typedef float f32x4 __attribute__((ext_vector_type(4)));
typedef float f32x2 __attribute__((ext_vector_type(2)));
typedef int   i32x4 __attribute__((ext_vector_type(4)));
typedef int   i32x8 __attribute__((ext_vector_type(8)));

#define LOG_SQRT_2PI 0.91893853320467274f

static constexpr int BSZ  = 16384;
static constexpr int OBSN = 376;
static constexpr int HD   = 512;
static constexpr int NACT = 17;

__device__ __forceinline__ unsigned char f2fp8(float v) {
  return (unsigned char)(__builtin_amdgcn_cvt_pk_fp8_f32(v, v, 0, false) & 0xFF);
}

// XCD-aware tile remap: blocks sharing an A-tile (same y,z; all x) get consecutive
// slots on the SAME XCD (id%8 round-robin). Requires gy*gz % 8 == 0.
__device__ __forceinline__ void xcd_map(int id, int gx, int gy, int& bx, int& by, int& bz) {
  int p = id & 7, l = id >> 3;
  bx = l % gx;
  int g = (l / gx) * 8 + p;
  by = g % gy;
  bz = g / gy;
}

// ---------------- prep kernels ----------------

// x [B,376] f32 -> [B,512] fp8 (zero pad)
__global__ void k_cvt_pad8(const float* __restrict__ src, unsigned char* __restrict__ dst) {
  long i = (long)blockIdx.x * 256 + threadIdx.x;
  if (i >= (long)BSZ * HD) return;
  long r = i >> 9;
  int  c = (int)(i & 511);
  dst[i] = f2fp8(c < OBSN ? src[r * OBSN + c] : 0.f);
}

// dst[n][k] = fp8(scale * src[k][n]); zero for k >= K. batched via blockIdx.z.
__global__ void k_packT8(const float* __restrict__ src, unsigned char* __restrict__ dst,
                         int K, int N, int Kpad, long sstride, long dstride, float scale) {
  __shared__ float t[32][33];
  src += (long)blockIdx.z * sstride;
  dst += (long)blockIdx.z * dstride;
  int k0 = blockIdx.y * 32, n0 = blockIdx.x * 32;
#pragma unroll
  for (int ii = 0; ii < 4; ++ii) {
    int i = ii * 8 + threadIdx.y;
    int k = k0 + i, n = n0 + threadIdx.x;
    t[i][threadIdx.x] = (k < K && n < N) ? src[(long)k * N + n] : 0.f;
  }
  __syncthreads();
#pragma unroll
  for (int ii = 0; ii < 4; ++ii) {
    int i = ii * 8 + threadIdx.y;
    int n = n0 + i, k = k0 + threadIdx.x;
    if (n < N && k < Kpad) dst[(long)n * Kpad + k] = f2fp8(scale * t[threadIdx.x][i]);
  }
}

// base-net weights: dst[z][n][k] = fp8(16 * src_z[k][n]); z<24 -> a_W, else c_W
__global__ void k_packw8(const float* __restrict__ aW, const float* __restrict__ cW,
                         unsigned char* __restrict__ dst) {
  __shared__ float t[32][33];
  const int z = blockIdx.z;
  const float* src = (z < 24) ? aW + (long)z * 262144 : cW + (long)(z - 24) * 262144;
  unsigned char* d = dst + (long)z * 262144;
  int k0 = blockIdx.y * 32, n0 = blockIdx.x * 32;
#pragma unroll
  for (int ii = 0; ii < 4; ++ii) {
    int i = ii * 8 + threadIdx.y;
    t[i][threadIdx.x] = src[(long)(k0 + i) * 512 + n0 + threadIdx.x];
  }
  __syncthreads();
#pragma unroll
  for (int ii = 0; ii < 4; ++ii) {
    int i = ii * 8 + threadIdx.y;
    d[(long)(n0 + i) * 512 + k0 + threadIdx.x] = f2fp8(16.f * t[threadIdx.x][i]);
  }
}

// final-head weights -> fp8, x64 scaled, transposed [32 pad][4096]
__global__ void k_packwf8(const float* __restrict__ aWf, const float* __restrict__ cWf,
                          unsigned char* __restrict__ dsta, unsigned char* __restrict__ dstc) {
  int i = blockIdx.x * 256 + threadIdx.x;   // 131072 total
  int n = i >> 12, k = i & 4095;
  dsta[i] = (n < NACT) ? f2fp8(64.f * aWf[(long)k * NACT + n]) : (unsigned char)0;
  dstc[i] = (n < 1)    ? f2fp8(64.f * cWf[k])                  : (unsigned char)0;
}

__global__ void k_pack_rb(const float* __restrict__ a_rb, const float* __restrict__ c_rb,
                          float* __restrict__ rb) {
  int i = threadIdx.x;  // 384 threads
  rb[i] = (i < 192) ? a_rb[i] : c_rb[i - 192];
}

__global__ void k_sum_bf(const float* __restrict__ a_bf, const float* __restrict__ c_bf,
                         float* __restrict__ sa, float* __restrict__ sc) {
  int a = threadIdx.x;
  if (a < NACT) { float s = 0.f; for (int m = 0; m < 8; ++m) s += a_bf[m * NACT + a]; sa[a] = s; }
  if (a == 0)   { float s = 0.f; for (int m = 0; m < 8; ++m) s += c_bf[m];            sc[0] = s; }
}

// ---------------- unified MX fp8 GEMM: acc = A8[rows,K] * (16*W)^T ; v = acc/16 + bias ----
// K=128 per MFMA via mfma_scale_f32_16x16x128_f8f6f4 (scales = 1.0, fmt 0 = e4m3).
// LDS rows 128 B; 16-B chunk g of row r stored at slot g ^ (r&7); reads lane-const swizzled.
// Operands SWAPPED (bv first): lane's 4 acc regs = 4 consecutive C cols -> dword/float4 stores.
// OP: 0 = relu -> fp8        (base-net layers)
//     1 = tanh -> fp8        (encoder-1)
//     5 = tanh -> fp8 (fs8) AND fp8(relu(tanh*temb[tidx])) -> out2 (encoder-2)
//     4 = softmax over col-octets -> f32 (routing; octet = quad-pair, shfl_xor 16)
template <int OP>
__global__ __launch_bounds__(256)
void k_gemm8(const unsigned char* __restrict__ A, const unsigned char* __restrict__ Bt,
             void* __restrict__ Cv, const float* __restrict__ bias,
             int N, int K, int lda, int ldc, int gx, int gy,
             int a_zoff, int b_zoff, int c_zoff, int bias_zoff,
             const int* __restrict__ tidx, const float* __restrict__ temb,
             unsigned char* __restrict__ out2) {
  __shared__ alignas(16) unsigned char sA[128 * 128];
  __shared__ alignas(16) unsigned char sB[128 * 128];
  int bx, by, z;
  xcd_map(blockIdx.x, gx, gy, bx, by, z);
  A  += (long)z * a_zoff;
  Bt += (long)z * b_zoff;
  const int tid  = threadIdx.x;
  const int wave = tid >> 6, lane = tid & 63;
  const int wr = (wave >> 1) * 64, wc = (wave & 1) * 64;
  const int row0 = by * 128, col0 = bx * 128;
  const int lcol = lane & 15, quad = lane >> 4;
  const int sw7 = lcol & 7;
  const int c0 = ((2 * quad)     ^ sw7) * 16;
  const int c1 = ((2 * quad + 1) ^ sw7) * 16;

  f32x4 acc[4][4] = {};

  for (int kt = 0; kt < K; kt += 128) {
#pragma unroll
    for (int i = 0; i < 4; ++i) {
      int u = i * 256 + tid;
      int r = u >> 3, gc = (u & 7) ^ (r & 7);
      const unsigned char* ga = A + (long)(row0 + r) * lda + kt + gc * 16;
      __builtin_amdgcn_global_load_lds((const __attribute__((address_space(1))) void*)ga,
                                       (__attribute__((address_space(3))) void*)&sA[u * 16], 16, 0, 0);
    }
#pragma unroll
    for (int i = 0; i < 4; ++i) {
      int u = i * 256 + tid;
      int r = u >> 3, gc = (u & 7) ^ (r & 7);
      const unsigned char* gb = Bt + (long)(col0 + r) * K + kt + gc * 16;
      __builtin_amdgcn_global_load_lds((const __attribute__((address_space(1))) void*)gb,
                                       (__attribute__((address_space(3))) void*)&sB[u * 16], 16, 0, 0);
    }
    __syncthreads();
    i32x8 af[4], bv[4];
#pragma unroll
    for (int t = 0; t < 4; ++t) {
      int ra = (wr + t * 16 + lcol) * 128;
      int rb = (wc + t * 16 + lcol) * 128;
      i32x4 alo = *(const i32x4*)&sA[ra + c0];
      i32x4 ahi = *(const i32x4*)&sA[ra + c1];
      i32x4 blo = *(const i32x4*)&sB[rb + c0];
      i32x4 bhi = *(const i32x4*)&sB[rb + c1];
      af[t] = (i32x8){alo[0], alo[1], alo[2], alo[3], ahi[0], ahi[1], ahi[2], ahi[3]};
      bv[t] = (i32x8){blo[0], blo[1], blo[2], blo[3], bhi[0], bhi[1], bhi[2], bhi[3]};
    }
#pragma unroll
    for (int mi = 0; mi < 4; ++mi)
#pragma unroll
      for (int ni = 0; ni < 4; ++ni)
        acc[mi][ni] = __builtin_amdgcn_mfma_scale_f32_16x16x128_f8f6f4(
            bv[ni], af[mi], acc[mi][ni], 0, 0, 0, 0x7F, 0, 0x7F);
    __syncthreads();
  }

  // acc[mi][ni][r] = C[row0+wr+mi*16+lcol][col0+wc+ni*16+quad*4+r]
#pragma unroll
  for (int ni = 0; ni < 4; ++ni) {
    int colb = col0 + wc + ni * 16 + quad * 4;
    if (colb >= N) continue;
    float4 bw = *(const float4*)&bias[(long)z * bias_zoff + colb];
#pragma unroll
    for (int mi = 0; mi < 4; ++mi) {
      int rowg = row0 + wr + mi * 16 + lcol;
      float v0 = acc[mi][ni][0] * 0.0625f + bw.x;
      float v1 = acc[mi][ni][1] * 0.0625f + bw.y;
      float v2 = acc[mi][ni][2] * 0.0625f + bw.z;
      float v3 = acc[mi][ni][3] * 0.0625f + bw.w;
      long idx = (long)rowg * ldc + (long)z * c_zoff + colb;
      if (OP == 0) {
        unsigned d = __builtin_amdgcn_cvt_pk_fp8_f32(fmaxf(v0, 0.f), fmaxf(v1, 0.f), 0, false);
        d = __builtin_amdgcn_cvt_pk_fp8_f32(fmaxf(v2, 0.f), fmaxf(v3, 0.f), d, true);
        *(unsigned*)&((unsigned char*)Cv)[idx] = d;
      } else if (OP == 1) {
        float t0 = tanhf(v0), t1 = tanhf(v1), t2 = tanhf(v2), t3 = tanhf(v3);
        unsigned d = __builtin_amdgcn_cvt_pk_fp8_f32(t0, t1, 0, false);
        d = __builtin_amdgcn_cvt_pk_fp8_f32(t2, t3, d, true);
        *(unsigned*)&((unsigned char*)Cv)[idx] = d;
      } else if (OP == 5) {
        float t0 = tanhf(v0), t1 = tanhf(v1), t2 = tanhf(v2), t3 = tanhf(v3);
        unsigned d = __builtin_amdgcn_cvt_pk_fp8_f32(t0, t1, 0, false);
        d = __builtin_amdgcn_cvt_pk_fp8_f32(t2, t3, d, true);
        *(unsigned*)&((unsigned char*)Cv)[idx] = d;
        int tk = tidx[rowg];
        float4 te = *(const float4*)&temb[(long)tk * HD + colb];
        unsigned e = __builtin_amdgcn_cvt_pk_fp8_f32(fmaxf(t0 * te.x, 0.f), fmaxf(t1 * te.y, 0.f), 0, false);
        e = __builtin_amdgcn_cvt_pk_fp8_f32(fmaxf(t2 * te.z, 0.f), fmaxf(t3 * te.w, 0.f), e, true);
        *(unsigned*)&out2[idx] = e;
      } else if (OP == 4) {
        // softmax over octet of 8 cols: this lane holds 4, partner (quad^1, xor 16) holds 4
        float mx = fmaxf(fmaxf(v0, v1), fmaxf(v2, v3));
        mx = fmaxf(mx, __shfl_xor(mx, 16));
        float e0 = __expf(v0 - mx), e1 = __expf(v1 - mx), e2 = __expf(v2 - mx), e3 = __expf(v3 - mx);
        float s = e0 + e1 + e2 + e3;
        s += __shfl_xor(s, 16);
        float inv = 1.f / s;
        *(float4*)&((float*)Cv)[idx] = make_float4(e0 * inv, e1 * inv, e2 * inv, e3 * inv);
      }
    }
  }
}

// ---------------- fp8 combine: g[b][i][h] = sum_j probs[b][i][j] * outs[b][j][h] ----------------
__global__ __launch_bounds__(256)
void k_combine8(const unsigned char* __restrict__ outs, const float* __restrict__ probs,
                unsigned char* __restrict__ g, int poff) {
  __shared__ float P[4][64];
  const int w = threadIdx.x >> 6, l = threadIdx.x & 63;
  const long b = (long)blockIdx.x * 4 + w;
  P[w][l] = probs[b * 384 + poff + l];
  __syncthreads();
  const unsigned char* ob = outs + b * 4096 + l * 8;
  float o[8][8];
#pragma unroll
  for (int j = 0; j < 8; ++j) {
    uint2 v = *(const uint2*)(ob + j * 512);
    f32x2 p01 = __builtin_amdgcn_cvt_pk_f32_fp8(v.x, false);
    f32x2 p23 = __builtin_amdgcn_cvt_pk_f32_fp8(v.x, true);
    f32x2 p45 = __builtin_amdgcn_cvt_pk_f32_fp8(v.y, false);
    f32x2 p67 = __builtin_amdgcn_cvt_pk_f32_fp8(v.y, true);
    o[j][0] = p01.x; o[j][1] = p01.y; o[j][2] = p23.x; o[j][3] = p23.y;
    o[j][4] = p45.x; o[j][5] = p45.y; o[j][6] = p67.x; o[j][7] = p67.y;
  }
  unsigned char* gb = g + b * 4096 + l * 8;
#pragma unroll
  for (int i = 0; i < 8; ++i) {
    float a[8] = {};
#pragma unroll
    for (int j = 0; j < 8; ++j) {
      float pw = P[w][i * 8 + j];
#pragma unroll
      for (int c = 0; c < 8; ++c) a[c] += pw * o[j][c];
    }
    unsigned int lo = __builtin_amdgcn_cvt_pk_fp8_f32(a[0], a[1], 0, false);
    lo = __builtin_amdgcn_cvt_pk_fp8_f32(a[2], a[3], lo, true);
    unsigned int hi = __builtin_amdgcn_cvt_pk_fp8_f32(a[4], a[5], 0, false);
    hi = __builtin_amdgcn_cvt_pk_fp8_f32(a[6], a[7], hi, true);
    *(uint2*)(gb + i * 512) = make_uint2(lo, hi);
  }
}

// ---------------- MFMA head: out[:, ooff..ooff+NOUT) = g8[rows,4096] * (64*Wf)^T / 64 + bsum ----
template <int NOUT>
__global__ __launch_bounds__(256)
void k_head8(const unsigned char* __restrict__ A, const unsigned char* __restrict__ Bt,
             const float* __restrict__ bsum, float* __restrict__ out, int ooff) {
  __shared__ alignas(16) unsigned char sA[64 * 64];
  __shared__ alignas(16) unsigned char sB[32 * 64];
  const int tid = threadIdx.x;
  const int wave = tid >> 6, lane = tid & 63;
  const int row0 = blockIdx.x * 64;
  const int lcol = lane & 15, quad = lane >> 4;
  const int sw = (lcol >> 1) & 3;
  const int co0 = (((quad >> 1)    ) ^ sw) * 16 + (quad & 1) * 8;
  const int co1 = (((quad >> 1) + 2) ^ sw) * 16 + (quad & 1) * 8;
  f32x4 acc[2] = {};

  for (int kt = 0; kt < 4096; kt += 64) {
    {
      int r = tid >> 2, gc = (tid & 3) ^ ((tid >> 3) & 3);
      const unsigned char* ga = A + (long)(row0 + r) * 4096 + kt + gc * 16;
      __builtin_amdgcn_global_load_lds((const __attribute__((address_space(1))) void*)ga,
                                       (__attribute__((address_space(3))) void*)&sA[tid * 16], 16, 0, 0);
    }
    if (tid < 128) {
      int r = tid >> 2, gc = (tid & 3) ^ ((tid >> 3) & 3);
      const unsigned char* gb = Bt + (long)r * 4096 + kt + gc * 16;
      __builtin_amdgcn_global_load_lds((const __attribute__((address_space(1))) void*)gb,
                                       (__attribute__((address_space(3))) void*)&sB[tid * 16], 16, 0, 0);
    }
    __syncthreads();
    long af[2], bv[2][2];
    int ra = (wave * 16 + lcol) * 64;
    af[0] = *(const long*)&sA[ra + co0];
    af[1] = *(const long*)&sA[ra + co1];
#pragma unroll
    for (int ni = 0; ni < 2; ++ni) {
      int rb = (ni * 16 + lcol) * 64;
      bv[0][ni] = *(const long*)&sB[rb + co0];
      bv[1][ni] = *(const long*)&sB[rb + co1];
    }
#pragma unroll
    for (int kk = 0; kk < 2; ++kk)
#pragma unroll
      for (int ni = 0; ni < 2; ++ni)
        acc[ni] = __builtin_amdgcn_mfma_f32_16x16x32_fp8_fp8(af[kk], bv[kk][ni], acc[ni], 0, 0, 0);
    __syncthreads();
  }

#pragma unroll
  for (int ni = 0; ni < 2; ++ni) {
    int col = ni * 16 + lcol;
    if (col >= NOUT) continue;
#pragma unroll
    for (int r = 0; r < 4; ++r) {
      int row = row0 + wave * 16 + quad * 4 + r;
      out[(long)row * 20 + ooff + col] = acc[ni][r] * 0.015625f + bsum[col];
    }
  }
}

__global__ void k_logstd(const float* __restrict__ ls, float* __restrict__ out) {
  float lp = 0.f, ent = 0.f;
#pragma unroll
  for (int a = 0; a < NACT; ++a) {
    float v = ls[a];
    lp  += -v - LOG_SQRT_2PI;
    ent += 0.5f + LOG_SQRT_2PI + v;
  }
  long b = (long)blockIdx.x * 256 + threadIdx.x;
  if (b < BSZ) { out[b * 20 + 17] = lp; out[b * 20 + 18] = ent; }
}

// ---------------- host ----------------

extern "C" void kernel_launch(void* const* d_in, const int* in_sizes, int n_in,
                              void* d_out, int out_size, void* d_ws, size_t ws_size,
                              hipStream_t stream) {
  const float* x        = (const float*)d_in[0];
  const int*   task_idx = (const int*)d_in[1];
  const float* enc_W1   = (const float*)d_in[2];
  const float* enc_b1   = (const float*)d_in[3];
  const float* enc_W2   = (const float*)d_in[4];
  const float* enc_b2   = (const float*)d_in[5];
  const float* task_emb = (const float*)d_in[6];
  const float* a_rW     = (const float*)d_in[7];
  const float* a_rb     = (const float*)d_in[8];
  const float* c_rW     = (const float*)d_in[9];
  const float* c_rb     = (const float*)d_in[10];
  const float* a_W      = (const float*)d_in[11];
  const float* a_b      = (const float*)d_in[12];
  const float* a_Wf     = (const float*)d_in[13];
  const float* a_bf     = (const float*)d_in[14];
  const float* c_W      = (const float*)d_in[15];
  const float* c_b      = (const float*)d_in[16];
  const float* c_Wf     = (const float*)d_in[17];
  const float* c_bf     = (const float*)d_in[18];
  const float* logstd   = (const float*)d_in[19];
  float* out = (float*)d_out;

  char* ws = (char*)d_ws;
  size_t off = 0;
  auto carve = [&](size_t bytes) {
    char* p = ws + off;
    off += (bytes + 255) & ~(size_t)255;
    return p;
  };
  // ---- fixed region ----
  unsigned char* W8 = (unsigned char*)carve((size_t)48 * 262144);   // fp8 layer weights, x16
  unsigned char* W1T8 = (unsigned char*)carve((size_t)512 * 512);   // enc W1^T fp8 x16, K-pad 512
  unsigned char* W2T8 = (unsigned char*)carve((size_t)512 * 512);   // enc W2^T fp8 x16
  unsigned char* rWT8 = (unsigned char*)carve((size_t)384 * 512);   // routing W^T fp8 x16
  float* rball = (float*)carve(384 * 4);
  unsigned char* WfaT8 = (unsigned char*)carve((size_t)32 * 4096);  // head weights fp8 x64, padded
  unsigned char* WfcT8 = (unsigned char*)carve((size_t)32 * 4096);
  float* bfa   = (float*)carve(128 * 4);
  float* bfc   = (float*)carve(128 * 4);
  unsigned char* fs8 = (unsigned char*)carve((size_t)BSZ * HD);
  float* lgt   = (float*)carve((size_t)BSZ * 384 * 4);

  // ---- fp8 ping-pong region (prefer full batch: fewest dispatches) ----
  size_t remain = (ws_size > off) ? (ws_size - off) : 0;
  int Bc = 4096;
  for (int cand = BSZ; cand > 4096; cand >>= 1)
    if ((size_t)2 * cand * 4096 <= remain) { Bc = cand; break; }
  size_t half = (size_t)Bc * 4096;
  unsigned char* bufA8 = (unsigned char*)carve(half);
  unsigned char* bufB8 = (unsigned char*)carve(half);
  unsigned char* x8   = bufA8;   // [B,512] fp8, dead after enc1
  unsigned char* h18  = bufB8;   // [B,512] fp8, dead after enc2
  unsigned char* rel8 = bufA8;   // [B,512] fp8, dead after routing

  dim3 tb(32, 8);

  // ---- prep (all fp8 packs) ----
  k_cvt_pad8<<<(int)(((long)BSZ * HD + 255) / 256), 256, 0, stream>>>(x, x8);
  k_packT8<<<dim3(16, 16, 1), tb, 0, stream>>>(enc_W1, W1T8, OBSN, 512, 512, 0, 0, 16.f);
  k_packT8<<<dim3(16, 16, 1), tb, 0, stream>>>(enc_W2, W2T8, 512, 512, 512, 0, 0, 16.f);
  k_packT8<<<dim3(2, 16, 3),  tb, 0, stream>>>(a_rW, rWT8,             512, 64, 512, 512 * 64, 64 * 512, 16.f);
  k_packT8<<<dim3(2, 16, 3),  tb, 0, stream>>>(c_rW, rWT8 + 192 * 512, 512, 64, 512, 512 * 64, 64 * 512, 16.f);
  k_packw8<<<dim3(16, 16, 48), tb, 0, stream>>>(a_W, c_W, W8);
  k_packwf8<<<512, 256, 0, stream>>>(a_Wf, c_Wf, WfaT8, WfcT8);
  k_pack_rb<<<1, 384, 0, stream>>>(a_rb, c_rb, rball);
  k_sum_bf<<<1, 32, 0, stream>>>(a_bf, c_bf, bfa, bfc);

  const int GY = BSZ / 128;
  // ---- encoder + routing (fp8 MX) ----
  k_gemm8<1><<<4 * GY, 256, 0, stream>>>(x8, W1T8, h18, enc_b1, 512, 512, 512, 512,
                                         4, GY, 0, 0, 0, 0, nullptr, nullptr, nullptr);
  k_gemm8<5><<<4 * GY, 256, 0, stream>>>(h18, W2T8, fs8, enc_b2, 512, 512, 512, 512,
                                         4, GY, 0, 0, 0, 0, task_idx, task_emb, rel8);
  k_gemm8<4><<<3 * GY, 256, 0, stream>>>(rel8, rWT8, lgt, rball, 384, 512, 512, 384,
                                         3, GY, 0, 0, 0, 0, nullptr, nullptr, nullptr);

  // ---- base nets (fp8 MX), chunked (Bc normally = 16384) ----
  const size_t wz8 = (size_t)8 * 262144;
  const unsigned char* W8a = W8;
  const unsigned char* W8c = W8 + (size_t)24 * 262144;
  for (int c0 = 0; c0 < BSZ; c0 += Bc) {
    const unsigned char* fs_c = fs8 + (long)c0 * 512;
    const float* pr_c  = lgt + (long)c0 * 384;
    float*       out_c = out + (long)c0 * 20;
    const int gy = Bc / 128;

    // critic
    k_gemm8<0><<<32 * gy, 256, 0, stream>>>(fs_c, W8c, bufA8, c_b, 4096, 512, 512, 4096,
                                            32, gy, 0, 0, 0, 0, nullptr, nullptr, nullptr);
    k_combine8<<<Bc / 4, 256, 0, stream>>>(bufA8, pr_c, bufB8, 192 + 0);
    k_gemm8<0><<<4 * gy * 8, 256, 0, stream>>>(bufB8, W8c + 1 * wz8, bufA8, c_b + 4096,
                                               512, 512, 4096, 4096, 4, gy, 512, 262144, 512, 512,
                                               nullptr, nullptr, nullptr);
    k_combine8<<<Bc / 4, 256, 0, stream>>>(bufA8, pr_c, bufB8, 192 + 64);
    k_gemm8<0><<<4 * gy * 8, 256, 0, stream>>>(bufB8, W8c + 2 * wz8, bufA8, c_b + 8192,
                                               512, 512, 4096, 4096, 4, gy, 512, 262144, 512, 512,
                                               nullptr, nullptr, nullptr);
    k_combine8<<<Bc / 4, 256, 0, stream>>>(bufA8, pr_c, bufB8, 192 + 128);
    k_head8<1><<<Bc / 64, 256, 0, stream>>>(bufB8, WfcT8, bfc, out_c, 19);

    // actor
    k_gemm8<0><<<32 * gy, 256, 0, stream>>>(fs_c, W8a, bufA8, a_b, 4096, 512, 512, 4096,
                                            32, gy, 0, 0, 0, 0, nullptr, nullptr, nullptr);
    k_combine8<<<Bc / 4, 256, 0, stream>>>(bufA8, pr_c, bufB8, 0);
    k_gemm8<0><<<4 * gy * 8, 256, 0, stream>>>(bufB8, W8a + 1 * wz8, bufA8, a_b + 4096,
                                               512, 512, 4096, 4096, 4, gy, 512, 262144, 512, 512,
                                               nullptr, nullptr, nullptr);
    k_combine8<<<Bc / 4, 256, 0, stream>>>(bufA8, pr_c, bufB8, 64);
    k_gemm8<0><<<4 * gy * 8, 256, 0, stream>>>(bufB8, W8a + 2 * wz8, bufA8, a_b + 8192,
                                               512, 512, 4096, 4096, 4, gy, 512, 262144, 512, 512,
                                               nullptr, nullptr, nullptr);
    k_combine8<<<Bc / 4, 256, 0, stream>>>(bufA8, pr_c, bufB8, 128);
    k_head8<NACT><<<Bc / 64, 256, 0, stream>>>(bufB8, WfaT8, bfa, out_c, 0);
  }

  // ---- constants ----
  k_logstd<<<BSZ / 256, 256, 0, stream>>>(logstd, out);
}